// Round 4
// baseline (1180.145 us; speedup 1.0000x reference)
//
#include <hip/hip_runtime.h>

// Top2Gating: B=4, N=4096, D=1024, E=64, capacity=128
// Outputs (flat in d_out): dispatch [B,N,E,C], combine [B,N,E,C], loss, z_loss
//
// Time model: ~900 us fixed harness poison/restore (timed, uncontrollable);
// controllable floor = 1.074 GB out-write + 67 MB x-read at ~6.3 TB/s ~ 183 us.
// Structure: k1 = gating (256 blk) + zero of dispatch half (4096 blk) overlapped;
// k2 = per-(b,e) capacity scan, streams the combine half (zeros+values inline),
// scatters 1.0 into dispatch half, reduces losses. No memset, no global atomic
// accumulators needing init.

#define B_DIM 4
#define N_DIM 4096
#define D_DIM 1024
#define E_DIM 64
#define CAP   128
#define NTOK  16384
#define TM    64                 // tokens per gating block
#define TK    64                 // k-chunk
#define GATE_BLOCKS 256          // NTOK/TM
#define ZERO_BLOCKS 4096         // dispatch half: 33554432 float4 / 8192 per blk

// ---------------- ws layout (bytes) ----------------
#define WS_IDX1  0        // 16384 int
#define WS_IDX2  65536
#define WS_G1    131072
#define WS_G2    196608
#define WS_DENS  262144   // 256 gating blocks x 64 experts floats (partials)
#define WS_Z     327680   // 256 floats (per-gating-block z partials)

// Kernel 1: block-role fused.
//  blocks [0,256):     router GEMM (fp64 acc, 4x4 tile) + softmax/top2
//  blocks [256,4352):  zero the dispatch half (537 MB) + the 2 loss scalars
__global__ __launch_bounds__(256) void fused_gating_zero(
    const float* __restrict__ x, const float* __restrict__ w,
    int* __restrict__ idx1, int* __restrict__ idx2,
    float* __restrict__ g1o, float* __restrict__ g2o,
    float* __restrict__ densPart, float* __restrict__ zPart,
    float* __restrict__ out, size_t half) {
  __shared__ __align__(16) char smem[33792];  // As 17408 + Bs 16384; Ld 33280 overlaid
  const int t = threadIdx.x;

  if (blockIdx.x >= GATE_BLOCKS) {
    const int zb = blockIdx.x - GATE_BLOCKS;
    float4* o4 = (float4*)out;
    const size_t base = (size_t)zb * 8192 + t;
    const float4 z = make_float4(0.f, 0.f, 0.f, 0.f);
#pragma unroll
    for (int i = 0; i < 32; ++i) o4[base + (size_t)i * 256] = z;
    if (zb == 0 && t == 0) { out[2 * half] = 0.f; out[2 * half + 1] = 0.f; }
    return;
  }

  // ---- gating role: 64 tokens x 64 experts per block, thread = 4 tok x 4 exp ----
  float (*As)[68] = (float(*)[68])smem;             // [64 tok][64 k] pad 68
  float (*Bs)[64] = (float(*)[64])(smem + 17408);   // [64 k][64 e]
  double (*Ld)[65] = (double(*)[65])smem;           // fp64 logits, overlaid

  const int tokBase = blockIdx.x * TM;
  const int tok0 = 4 * (t >> 4), e0 = 4 * (t & 15);

  double acc[4][4] = {};

  for (int k0 = 0; k0 < D_DIM; k0 += TK) {
    {
      const int d4 = t & 15, rowb = t >> 4;
#pragma unroll
      for (int r = 0; r < 4; ++r) {
        float4 v = *(const float4*)(x + (size_t)(tokBase + rowb + 16 * r) * D_DIM + k0 + 4 * d4);
        *(float4*)&As[rowb + 16 * r][4 * d4] = v;
      }
      const float4* wsrc = (const float4*)(w + (size_t)k0 * E_DIM);
      float4* bdst = (float4*)&Bs[0][0];
#pragma unroll
      for (int i = 0; i < 4; ++i) bdst[t + 256 * i] = wsrc[t + 256 * i];
    }
    __syncthreads();
#pragma unroll 4
    for (int kk = 0; kk < TK; ++kk) {
      float4 bv = *(float4*)&Bs[kk][e0];
      double b0 = bv.x, b1 = bv.y, b2 = bv.z, b3 = bv.w;
      double a0 = As[tok0][kk], a1 = As[tok0 + 1][kk];
      double a2 = As[tok0 + 2][kk], a3 = As[tok0 + 3][kk];
      acc[0][0] += a0 * b0; acc[0][1] += a0 * b1; acc[0][2] += a0 * b2; acc[0][3] += a0 * b3;
      acc[1][0] += a1 * b0; acc[1][1] += a1 * b1; acc[1][2] += a1 * b2; acc[1][3] += a1 * b3;
      acc[2][0] += a2 * b0; acc[2][1] += a2 * b1; acc[2][2] += a2 * b2; acc[2][3] += a2 * b3;
      acc[3][0] += a3 * b0; acc[3][1] += a3 * b1; acc[3][2] += a3 * b2; acc[3][3] += a3 * b3;
    }
    __syncthreads();
  }

#pragma unroll
  for (int i = 0; i < 4; ++i)
#pragma unroll
    for (int j = 0; j < 4; ++j) Ld[tok0 + i][e0 + j] = acc[i][j];
  __syncthreads();

  // softmax/top2: 4 waves x 16 tokens; lane = expert
  const int wv = t >> 6, lane = t & 63;
  float densacc = 0.f, zacc = 0.f;

  for (int s = 0; s < 16; ++s) {
    const int tok = wv * 16 + s;
    const double l = Ld[tok][lane];

    double mv = l; int mi = lane;
#pragma unroll
    for (int off = 32; off; off >>= 1) {
      double ov = __shfl_xor(mv, off);
      int oi = __shfl_xor(mi, off);
      if (ov > mv || (ov == mv && oi < mi)) { mv = ov; mi = oi; }
    }
    float p = expf((float)(l - mv));
    float sum = p;
#pragma unroll
    for (int off = 32; off; off >>= 1) sum += __shfl_xor(sum, off);

    double l2 = (lane == mi) ? -1.0e300 : l;
    double mv2 = l2; int mi2 = lane;
#pragma unroll
    for (int off = 32; off; off >>= 1) {
      double ov = __shfl_xor(mv2, off);
      int oi = __shfl_xor(mi2, off);
      if (ov > mv2 || (ov == mv2 && oi < mi2)) { mv2 = ov; mi2 = oi; }
    }

    float gate1 = 1.0f / sum;
    float gate2 = expf((float)(mv2 - mv)) / sum;
    float denom = gate1 + gate2 + 1e-9f;
    float g1n = gate1 / denom, g2n = gate2 / denom;
    int i2eff = (g2n > 0.2f) ? mi2 : -1;
    float lse = (float)mv + logf(sum);

    densacc += p / sum;                    // softmax prob = density_proxy term
    if (lane == 0) {
      const int gt = tokBase + tok;
      idx1[gt] = mi; idx2[gt] = i2eff;
      g1o[gt] = g1n; g2o[gt] = g2n;
      zacc += lse;
    }
  }

  // per-block partial reductions (no global atomics, no pre-zero needed)
  __syncthreads();
  float* Ldns = (float*)smem;        // [4][64]
  float* Lz = (float*)(smem + 1024); // [4]
  Ldns[wv * 64 + lane] = densacc;
  if (lane == 0) Lz[wv] = zacc;
  __syncthreads();
  if (wv == 0) {
    float d = Ldns[lane] + Ldns[64 + lane] + Ldns[128 + lane] + Ldns[192 + lane];
    densPart[(blockIdx.x << 6) + lane] = d;
    if (lane == 0) zPart[blockIdx.x] = Lz[0] + Lz[1] + Lz[2] + Lz[3];
  }
}

// Kernel 2: per-(b,e) capacity scan + full combine-half stream + dispatch scatter
// + loss reduction. 256 blocks (one per b,e) x 256 threads.
__global__ __launch_bounds__(256) void scan_write(
    const int* __restrict__ idx1, const int* __restrict__ idx2,
    const float* __restrict__ g1, const float* __restrict__ g2,
    const float* __restrict__ densPart, const float* __restrict__ zPart,
    float* __restrict__ out, size_t half) {
  __shared__ unsigned char posv[N_DIM];  // capacity slot per token (0xFF = none)
  __shared__ float valv[N_DIM];          // gate value for matched tokens
  __shared__ int wcnt[4];

  const int bid = blockIdx.x, b = bid >> 6, e = bid & 63;
  const int wv = threadIdx.x >> 6, lane = threadIdx.x & 63;
  const int tokBase = b * N_DIM + wv * 1024;  // global token base of this wave's strip
  const unsigned long long lmask = (1ull << lane) - 1ull;

  float* dispatch = out;

  ((int4*)posv)[threadIdx.x] = make_int4(-1, -1, -1, -1);
  __syncthreads();

  unsigned long long bal[16];

  // ---- phase 1: top-1 ----
  int c = 0;
#pragma unroll
  for (int ch = 0; ch < 16; ++ch) {
    bool m = (idx1[tokBase + ch * 64 + lane] == e);
    bal[ch] = __ballot(m);
    c += __popcll(bal[ch]);
  }
  if (lane == 0) wcnt[wv] = c;
  __syncthreads();
  int pre = 0, tot = 0;
#pragma unroll
  for (int wvi = 0; wvi < 4; ++wvi) {
    int v = wcnt[wvi];
    if (wvi < wv) pre += v;
    tot += v;
  }
  int run = pre;
#pragma unroll
  for (int ch = 0; ch < 16; ++ch) {
    unsigned long long bb = bal[ch];
    if ((bb >> lane) & 1ull) {
      int p = run + __popcll(bb & lmask);
      if (p < CAP) {
        int gt = tokBase + ch * 64 + lane;
        int tl = gt - b * N_DIM;
        posv[tl] = (unsigned char)p;
        valv[tl] = g1[gt];
        dispatch[((size_t)gt * E_DIM + e) * CAP + p] = 1.0f;
      }
    }
    run += __popcll(bb);
  }
  __syncthreads();  // wcnt reuse + posv/valv ordering

  // ---- phase 2: top-2, offset by min(tot, CAP) ----
  const int off0 = tot < CAP ? tot : CAP;
  int c2 = 0;
#pragma unroll
  for (int ch = 0; ch < 16; ++ch) {
    bool m = (idx2[tokBase + ch * 64 + lane] == e);
    bal[ch] = __ballot(m);
    c2 += __popcll(bal[ch]);
  }
  if (lane == 0) wcnt[wv] = c2;
  __syncthreads();
  int pre2 = 0;
#pragma unroll
  for (int wvi = 0; wvi < 4; ++wvi)
    if (wvi < wv) pre2 += wcnt[wvi];
  int run2 = off0 + pre2;
#pragma unroll
  for (int ch = 0; ch < 16; ++ch) {
    unsigned long long bb = bal[ch];
    if ((bb >> lane) & 1ull) {
      int p = run2 + __popcll(bb & lmask);
      if (p < CAP) {
        int gt = tokBase + ch * 64 + lane;
        int tl = gt - b * N_DIM;
        posv[tl] = (unsigned char)p;
        valv[tl] = g2[gt];
        dispatch[((size_t)gt * E_DIM + e) * CAP + p] = 1.0f;
      }
    }
    run2 += __popcll(bb);
  }

  // ---- losses (needs only phase-1 tot + global partials) ----
  if (wv == 0) {
    float v = densPart[(((b << 6) + lane) << 6) + e];
#pragma unroll
    for (int off = 32; off; off >>= 1) v += __shfl_xor(v, off);
    if (lane == 0)
      atomicAdd(&out[2 * half], v * (float)tot * (1.0f / 1048576.0f));
  }
  if (bid == 0 && wv == 1) {
    float v = zPart[lane] + zPart[lane + 64] + zPart[lane + 128] + zPart[lane + 192];
#pragma unroll
    for (int off = 32; off; off >>= 1) v += __shfl_xor(v, off);
    if (lane == 0) out[2 * half + 1] = v * 0.25f;
  }
  __syncthreads();  // posv/valv complete before streaming

  // ---- stream the combine half for this (b,e): 4096 rows x 128 floats ----
  const int grp = threadIdx.x >> 5, l = threadIdx.x & 31;
  float4* comb4 = (float4*)(out + half);
  for (int it = 0; it < 512; ++it) {
    const int tl = it * 8 + grp;
    const int pos = posv[tl];
    float4 v = make_float4(0.f, 0.f, 0.f, 0.f);
    if ((pos >> 2) == l) ((float*)&v)[pos & 3] = valv[tl];
    comb4[((size_t)(b * N_DIM + tl) * E_DIM + e) * 32 + l] = v;
  }
}

extern "C" void kernel_launch(void* const* d_in, const int* in_sizes, int n_in,
                              void* d_out, int out_size, void* d_ws, size_t ws_size,
                              hipStream_t stream) {
  const float* x = (const float*)d_in[0];
  const float* w = (const float*)d_in[1];
  float* out = (float*)d_out;
  char* ws = (char*)d_ws;

  int*   idx1 = (int*)(ws + WS_IDX1);
  int*   idx2 = (int*)(ws + WS_IDX2);
  float* g1   = (float*)(ws + WS_G1);
  float* g2   = (float*)(ws + WS_G2);
  float* densPart = (float*)(ws + WS_DENS);
  float* zPart    = (float*)(ws + WS_Z);

  const size_t half = ((size_t)out_size - 2) / 2;  // 134217728

  fused_gating_zero<<<GATE_BLOCKS + ZERO_BLOCKS, 256, 0, stream>>>(
      x, w, idx1, idx2, g1, g2, densPart, zPart, out, half);

  scan_write<<<B_DIM * E_DIM, 256, 0, stream>>>(idx1, idx2, g1, g2,
                                                densPart, zPart, out, half);
}

// Round 6
// 1108.413 us; speedup vs baseline: 1.0647x; 1.0647x over previous
//
#include <hip/hip_runtime.h>

// Top2Gating: B=4, N=4096, D=1024, E=64, capacity=128
// Outputs (flat in d_out): dispatch [B,N,E,C], combine [B,N,E,C], loss, z_loss
//
// Time model: ~900 us fixed harness poison/restore inside the timed window
// (686 us 0xAA fill of d_out at 4.295 GB + input restore + gaps).
// Controllable floor: 1.074 GB output write + 67 MB x read at ~6.3 TB/s ~ 183 us.
// Structure (R3, best so far): kernel 1 = full zero of d_out (8192 blocks,
// nontemporal 16B stores) overlapped with router gating (256 blocks, fp64 acc);
// kernel 2 = per-(b,e) capacity scan + sparse scatter + loss reduction.
// R4's lesson: do NOT stream the combine half from 256 blocks (2.5 TB/s only);
// pay the full-width fill instead.

#define B_DIM 4
#define N_DIM 4096
#define D_DIM 1024
#define E_DIM 64
#define CAP   128
#define NTOK  16384
#define TM    64                 // tokens per gating block
#define TK    64                 // k-chunk
#define GATE_BLOCKS 256          // NTOK/TM
#define ZERO_BLOCKS 8192         // 2*half floats = 67108864 x 16B / 8192 per blk

typedef float floatx4 __attribute__((ext_vector_type(4)));  // native vec for nontemporal

// ---------------- ws layout (bytes) ----------------
#define WS_IDX1  0        // 16384 int
#define WS_IDX2  65536
#define WS_G1    131072
#define WS_G2    196608
#define WS_DENS  262144   // [256 gating blocks][64 experts] float partials
#define WS_Z     327680   // 256 float (per-gating-block z partials)

// Kernel 1: block-role fused.
//  blocks [0,256):     router GEMM (fp64 acc, 4 tok x 4 exp per thread) + top2
//  blocks [256,8448):  nontemporal zero of the full 1.074 GB output + scalars
__global__ __launch_bounds__(256) void fused_gating_zero(
    const float* __restrict__ x, const float* __restrict__ w,
    int* __restrict__ idx1, int* __restrict__ idx2,
    float* __restrict__ g1o, float* __restrict__ g2o,
    float* __restrict__ densPart, float* __restrict__ zPart,
    float* __restrict__ out, size_t half) {
  __shared__ __align__(16) char smem[33792];  // As 17408 + Bs 16384; Ld 33280 overlaid
  const int t = threadIdx.x;

  if (blockIdx.x >= GATE_BLOCKS) {
    // ---- zero role: 8192 x 16B per block, nontemporal ----
    const int zb = blockIdx.x - GATE_BLOCKS;
    floatx4* o4 = (floatx4*)out;
    const size_t base = (size_t)zb * 8192 + t;
    const floatx4 z = {0.f, 0.f, 0.f, 0.f};
#pragma unroll
    for (int i = 0; i < 32; ++i)
      __builtin_nontemporal_store(z, &o4[base + (size_t)i * 256]);
    if (zb == 0 && t == 0) { out[2 * half] = 0.f; out[2 * half + 1] = 0.f; }
    return;
  }

  // ---- gating role: 64 tokens x 64 experts per block ----
  float (*As)[68] = (float(*)[68])smem;             // [64 tok][64 k] pad->68
  float (*Bs)[64] = (float(*)[64])(smem + 17408);   // [64 k][64 e]
  double (*Ld)[65] = (double(*)[65])smem;           // fp64 logits, overlaid post-loop

  const int tokBase = blockIdx.x * TM;
  const int tok0 = 4 * (t >> 4), e0 = 4 * (t & 15);

  double acc[4][4] = {};

  for (int k0 = 0; k0 < D_DIM; k0 += TK) {
    {
      const int d4 = t & 15, rowb = t >> 4;
#pragma unroll
      for (int r = 0; r < 4; ++r) {
        float4 v = *(const float4*)(x + (size_t)(tokBase + rowb + 16 * r) * D_DIM + k0 + 4 * d4);
        *(float4*)&As[rowb + 16 * r][4 * d4] = v;
      }
      const float4* wsrc = (const float4*)(w + (size_t)k0 * E_DIM);
      float4* bdst = (float4*)&Bs[0][0];
#pragma unroll
      for (int i = 0; i < 4; ++i) bdst[t + 256 * i] = wsrc[t + 256 * i];
    }
    __syncthreads();
#pragma unroll 4
    for (int kk = 0; kk < TK; ++kk) {
      float4 bv = *(float4*)&Bs[kk][e0];
      double b0 = bv.x, b1 = bv.y, b2 = bv.z, b3 = bv.w;
      double a0 = As[tok0][kk], a1 = As[tok0 + 1][kk];
      double a2 = As[tok0 + 2][kk], a3 = As[tok0 + 3][kk];
      acc[0][0] += a0 * b0; acc[0][1] += a0 * b1; acc[0][2] += a0 * b2; acc[0][3] += a0 * b3;
      acc[1][0] += a1 * b0; acc[1][1] += a1 * b1; acc[1][2] += a1 * b2; acc[1][3] += a1 * b3;
      acc[2][0] += a2 * b0; acc[2][1] += a2 * b1; acc[2][2] += a2 * b2; acc[2][3] += a2 * b3;
      acc[3][0] += a3 * b0; acc[3][1] += a3 * b1; acc[3][2] += a3 * b2; acc[3][3] += a3 * b3;
    }
    __syncthreads();
  }

#pragma unroll
  for (int i = 0; i < 4; ++i)
#pragma unroll
    for (int j = 0; j < 4; ++j) Ld[tok0 + i][e0 + j] = acc[i][j];
  __syncthreads();

  // softmax/top2: 4 waves x 16 tokens; lane = expert
  const int wv = t >> 6, lane = t & 63;
  float densacc = 0.f, zacc = 0.f;

  for (int s = 0; s < 16; ++s) {
    const int tok = wv * 16 + s;
    const double l = Ld[tok][lane];

    double mv = l; int mi = lane;
#pragma unroll
    for (int off = 32; off; off >>= 1) {
      double ov = __shfl_xor(mv, off);
      int oi = __shfl_xor(mi, off);
      if (ov > mv || (ov == mv && oi < mi)) { mv = ov; mi = oi; }
    }
    float p = expf((float)(l - mv));
    float sum = p;
#pragma unroll
    for (int off = 32; off; off >>= 1) sum += __shfl_xor(sum, off);

    double l2 = (lane == mi) ? -1.0e300 : l;
    double mv2 = l2; int mi2 = lane;
#pragma unroll
    for (int off = 32; off; off >>= 1) {
      double ov = __shfl_xor(mv2, off);
      int oi = __shfl_xor(mi2, off);
      if (ov > mv2 || (ov == mv2 && oi < mi2)) { mv2 = ov; mi2 = oi; }
    }

    float gate1 = 1.0f / sum;
    float gate2 = expf((float)(mv2 - mv)) / sum;
    float denom = gate1 + gate2 + 1e-9f;
    float g1n = gate1 / denom, g2n = gate2 / denom;
    int i2eff = (g2n > 0.2f) ? mi2 : -1;
    float lse = (float)mv + logf(sum);

    densacc += p / sum;                    // softmax prob (density_proxy term)
    if (lane == 0) {
      const int gt = tokBase + tok;
      idx1[gt] = mi; idx2[gt] = i2eff;
      g1o[gt] = g1n; g2o[gt] = g2n;
      zacc += lse;
    }
  }

  // per-block partial reductions -> ws (no global atomics, no pre-zero)
  __syncthreads();
  float* Ldns = (float*)smem;        // [4][64]
  float* Lz = (float*)(smem + 1024); // [4]
  Ldns[wv * 64 + lane] = densacc;
  if (lane == 0) Lz[wv] = zacc;
  __syncthreads();
  if (wv == 0) {
    float d = Ldns[lane] + Ldns[64 + lane] + Ldns[128 + lane] + Ldns[192 + lane];
    densPart[(blockIdx.x << 6) + lane] = d;
    if (lane == 0) zPart[blockIdx.x] = Lz[0] + Lz[1] + Lz[2] + Lz[3];
  }
}

// Kernel 2: per-(b,e) capacity scan + sparse scatter into pre-zeroed output
// + loss reduction from ws partials. 256 blocks x 256 threads.
__global__ __launch_bounds__(256) void scan_scatter(
    const int* __restrict__ idx1, const int* __restrict__ idx2,
    const float* __restrict__ g1, const float* __restrict__ g2,
    const float* __restrict__ densPart, const float* __restrict__ zPart,
    float* __restrict__ out, size_t half) {
  const int bid = blockIdx.x;          // 0..255 = b*64 + e
  const int b = bid >> 6, e = bid & 63;
  const int wv = threadIdx.x >> 6, lane = threadIdx.x & 63;
  const int tokBase = b * N_DIM + wv * 1024;
  const unsigned long long lmask = (1ull << lane) - 1ull;
  __shared__ int wcnt[4];

  float* dispatch = out;
  float* combine = out + half;
  unsigned long long bal[16];

  // ---- phase 1: top-1 ----
  int c = 0;
#pragma unroll
  for (int ch = 0; ch < 16; ++ch) {
    bool m = (idx1[tokBase + ch * 64 + lane] == e);
    bal[ch] = __ballot(m);
    c += __popcll(bal[ch]);
  }
  if (lane == 0) wcnt[wv] = c;
  __syncthreads();
  int pre = 0, tot = 0;
#pragma unroll
  for (int wvi = 0; wvi < 4; ++wvi) {
    int v = wcnt[wvi];
    if (wvi < wv) pre += v;
    tot += v;
  }
  int run = pre;
#pragma unroll
  for (int ch = 0; ch < 16; ++ch) {
    unsigned long long bb = bal[ch];
    if ((bb >> lane) & 1ull) {
      int p = run + __popcll(bb & lmask);
      if (p < CAP) {
        int tok = tokBase + ch * 64 + lane;
        size_t off = ((size_t)tok * E_DIM + e) * CAP + p;
        dispatch[off] = 1.0f;
        combine[off] = g1[tok];
      }
    }
    run += __popcll(bb);
  }
  __syncthreads();   // wcnt reuse

  // ---- phase 2: top-2, offset by min(tot, CAP) ----
  const int off0 = tot < CAP ? tot : CAP;
  int c2 = 0;
#pragma unroll
  for (int ch = 0; ch < 16; ++ch) {
    bool m = (idx2[tokBase + ch * 64 + lane] == e);
    bal[ch] = __ballot(m);
    c2 += __popcll(bal[ch]);
  }
  if (lane == 0) wcnt[wv] = c2;
  __syncthreads();
  int pre2 = 0;
#pragma unroll
  for (int wvi = 0; wvi < 4; ++wvi)
    if (wvi < wv) pre2 += wcnt[wvi];
  int run2 = off0 + pre2;
#pragma unroll
  for (int ch = 0; ch < 16; ++ch) {
    unsigned long long bb = bal[ch];
    if ((bb >> lane) & 1ull) {
      int p = run2 + __popcll(bb & lmask);
      if (p < CAP) {
        int tok = tokBase + ch * 64 + lane;
        size_t off = ((size_t)tok * E_DIM + e) * CAP + p;
        dispatch[off] = 1.0f;
        combine[off] = g2[tok];
      }
    }
    run2 += __popcll(bb);
  }

  // ---- losses ----
  if (wv == 0) {
    // sum over the 64 gating blocks of batch b for expert e
    float v = densPart[(((b << 6) + lane) << 6) + e];
#pragma unroll
    for (int off = 32; off; off >>= 1) v += __shfl_xor(v, off);
    if (lane == 0)
      atomicAdd(&out[2 * half], v * (float)tot * (1.0f / 1048576.0f));
  }
  if (bid == 0 && wv == 1) {
    float v = zPart[lane] + zPart[lane + 64] + zPart[lane + 128] + zPart[lane + 192];
#pragma unroll
    for (int off = 32; off; off >>= 1) v += __shfl_xor(v, off);
    if (lane == 0) out[2 * half + 1] = v * 0.25f;
  }
}

extern "C" void kernel_launch(void* const* d_in, const int* in_sizes, int n_in,
                              void* d_out, int out_size, void* d_ws, size_t ws_size,
                              hipStream_t stream) {
  const float* x = (const float*)d_in[0];
  const float* w = (const float*)d_in[1];
  float* out = (float*)d_out;
  char* ws = (char*)d_ws;

  int*   idx1 = (int*)(ws + WS_IDX1);
  int*   idx2 = (int*)(ws + WS_IDX2);
  float* g1   = (float*)(ws + WS_G1);
  float* g2   = (float*)(ws + WS_G2);
  float* densPart = (float*)(ws + WS_DENS);
  float* zPart    = (float*)(ws + WS_Z);

  const size_t half = ((size_t)out_size - 2) / 2;  // 134217728

  fused_gating_zero<<<GATE_BLOCKS + ZERO_BLOCKS, 256, 0, stream>>>(
      x, w, idx1, idx2, g1, g2, densPart, zPart, out, half);

  scan_scatter<<<B_DIM * E_DIM, 256, 0, stream>>>(idx1, idx2, g1, g2,
                                                  densPart, zPart, out, half);
}